// Round 1
// 472.474 us; speedup vs baseline: 1.0156x; 1.0156x over previous
//
#include <hip/hip_runtime.h>
#include <hip/hip_fp16.h>

#define NN 50000   // nodes
#define NE 100000  // edges
#define NB 512     // graphs
// H = 64, F_NODE = 16, F_EDGE = 8, T = 3

typedef _Float16 f16x8 __attribute__((ext_vector_type(8)));
typedef float f32x4  __attribute__((ext_vector_type(4)));

__device__ __forceinline__ float sigm(float v) { return 1.0f / (1.0f + __expf(-v)); }
__device__ __forceinline__ float tanh_fast(float v) {
    float e = __expf(-2.0f * fabsf(v));
    float t = (1.0f - e) / (1.0f + e);
    return v < 0.f ? -t : t;
}

// x[n][h] = node_features[n] . Win[h] + bin[h]; also write f16 copy xh
__global__ __launch_bounds__(256) void node_in_kernel(
    const float* __restrict__ nf, const float* __restrict__ Win,
    const float* __restrict__ bin_, float* __restrict__ x, __half* __restrict__ xh)
{
    int idx = blockIdx.x * 256 + threadIdx.x;
    if (idx >= NN * 64) return;
    int n = idx >> 6, h = idx & 63;
    float acc = bin_[h];
    #pragma unroll
    for (int f = 0; f < 16; f++) acc += nf[n * 16 + f] * Win[h * 16 + f];
    x[idx] = acc;
    xh[idx] = __float2half(acc);
}

// ehh[e][k] = f16(relu(edge_features[e] . We1[k] + be1[k]))
__global__ __launch_bounds__(256) void edge_l1_kernel(
    const float* __restrict__ ef, const float* __restrict__ We1,
    const float* __restrict__ be1, __half* __restrict__ ehh)
{
    int idx = blockIdx.x * 256 + threadIdx.x;
    if (idx >= NE * 64) return;
    int e = idx >> 6, k = idx & 63;
    float acc = be1[k];
    #pragma unroll
    for (int f = 0; f < 8; f++) acc += ef[e * 8 + f] * We1[k * 8 + f];
    ehh[idx] = __float2half(fmaxf(acc, 0.0f));
}

// Pack We2 (+ be2 K-extension) into LANE-LINEAR f16 MFMA-B-fragment order:
// Bp[kt*2048 + nt*512 + lane*8 + i]; lane = quad*16 + m;
//   n = nt*16 + m, kk = quad*8 + i, p = kt*32 + kk;
//   p<4096: We2[(n*64 + (p>>6))*64 + (p&63)], else be2[n*64 + (p-4096)]
// This makes both the LDS stage (tid-linear ds_write_b128) and the per-lane
// ds_read_b128 fully linear -> zero bank conflicts (rule 21: same permutation
// on write and read sides).
__global__ __launch_bounds__(256) void pack_b_kernel(
    const float* __restrict__ We2, const float* __restrict__ be2,
    __half* __restrict__ Bp)
{
    int idx = blockIdx.x * 256 + threadIdx.x;
    if (idx >= 130 * 2048) return;
    int i  = idx & 7;
    int l  = (idx >> 3) & 63;
    int nt = (idx >> 9) & 3;
    int kt = idx >> 11;
    int n  = nt * 16 + (l & 15);
    int kk = (l >> 4) * 8 + i;
    int p  = kt * 32 + kk;
    float v;
    if (p < 4096) {
        int j = p >> 6, k = p & 63;
        v = We2[((size_t)(n * 64 + j)) * 64 + k];
    } else {
        v = be2[n * 64 + (p - 4096)];
    }
    Bp[idx] = __float2half(v);
}

// Pack GRU weights into f16 B-frag layout WG[kt][nt][n][kk]:
// cols 0..383 = [i_r,i_z,i_n](Wih) ++ [h_r,h_z,h_n](Whh); nt tile = 16 cols; kt: K=64 in 2x32
__global__ __launch_bounds__(256) void pack_gru_kernel(
    const float* __restrict__ Wih, const float* __restrict__ Whh,
    __half* __restrict__ WG)
{
    int idx = blockIdx.x * 256 + threadIdx.x;   // 2*24*16*32 = 24576
    if (idx >= 24576) return;
    int kk = idx & 31;
    int n  = (idx >> 5) & 15;
    int nt = (idx >> 9) % 24;
    int kt = (idx >> 9) / 24;
    int k = kt * 32 + kk;
    int col192 = (nt % 12) * 16 + n;
    int gate = col192 >> 6, h = col192 & 63;
    const float* src = (nt < 12) ? Wih : Whh;
    WG[idx] = __float2half(src[((size_t)(gate * 64 + h)) * 64 + k]);
}

// Fused message GEMM, f16: msg[e][i] = sum_{j,k} We2[i*64+j][k]*x[src][j]*eh[e][k] (+be2.x)
// v2: 128 edges/block (4 waves x 32 edges) -> grid 782 blocks (~3 blocks/CU vs 1.5),
//     B staged through LDS double-buffered (read from L2 once per BLOCK, not per wave),
//     lane-linear B layout -> conflict-free ds_read_b128 / ds_write_b128.
__global__ __launch_bounds__(256, 3) void msg_kernel(
    const __half* __restrict__ xh, const __half* __restrict__ ehh,
    const __half* __restrict__ Bp,
    const int* __restrict__ Esrc, const int* __restrict__ Etgt,
    float* __restrict__ agg)
{
    __shared__ __half xs[4][32][72];   // 18432 B; 72: rows 144B, 2-way bank alias only
    __shared__ __half bbuf[2][4096];   // 2 x 8KB double buffer: per tile kt pair (2j, 2j+1)
    __shared__ int tgt_s[128];
    const int tid = threadIdx.x;
    const int e0 = blockIdx.x * 128;
    const int w = tid >> 6, lane = tid & 63;
    const int m = lane & 15, quad = lane >> 4;

    {   // stage gathered f16 source rows: 128 rows, 2 threads per row (64B each)
        const int r = tid >> 1, part = tid & 1;
        const int e = e0 + r;
        const bool ok = (e < NE);
        const int src = ok ? Esrc[e] : 0;
        if (part == 0) tgt_s[r] = ok ? Etgt[e] : -1;
        const uint4* xsrc = (const uint4*)(xh + (size_t)src * 64 + part * 32);
        __half* dst = &xs[r >> 5][r & 31][part * 32];
        #pragma unroll
        for (int i = 0; i < 4; i++) {
            uint4 v = ok ? xsrc[i] : make_uint4(0, 0, 0, 0);
            *(uint4*)(dst + i * 8) = v;
        }
    }

    {   // prologue: B tile 0 (kt 0,1) -> bbuf[0]; tid-linear, conflict-free
        const uint4* s = (const uint4*)Bp;
        uint4 v0 = s[tid], v1 = s[256 + tid];
        ((uint4*)bbuf[0])[tid] = v0;
        ((uint4*)bbuf[0])[256 + tid] = v1;
    }

    // per-lane eh f16 cache: pairs for k in {quad*8..+8} u {32+quad*8..+8}, 2 m-tiles
    __half2 ehc2[2][2][4];
    #pragma unroll
    for (int mt = 0; mt < 2; mt++) {
        const int e = e0 + w * 32 + mt * 16 + m;
        if (e < NE) {
            union { uint4 u; __half2 h[4]; } u0, u1;
            u0.u = *(const uint4*)(ehh + (size_t)e * 64 + quad * 8);
            u1.u = *(const uint4*)(ehh + (size_t)e * 64 + 32 + quad * 8);
            #pragma unroll
            for (int q = 0; q < 4; q++) { ehc2[mt][0][q] = u0.h[q]; ehc2[mt][1][q] = u1.h[q]; }
        } else {
            __half2 z = __halves2half2(__float2half(0.f), __float2half(0.f));
            #pragma unroll
            for (int q = 0; q < 4; q++) { ehc2[mt][0][q] = z; ehc2[mt][1][q] = z; }
        }
    }

    f32x4 acc[2][4];
    #pragma unroll
    for (int a = 0; a < 2; a++)
        #pragma unroll
        for (int b = 0; b < 4; b++)
            #pragma unroll
            for (int q = 0; q < 4; q++) acc[a][b][q] = 0.f;

    __syncthreads();   // xs + bbuf[0] ready

    int cur = 0;
    #pragma unroll 1
    for (int j = 0; j < 64; j++) {
        // T14 async-stage: issue next B tile's loads before compute (latency hides
        // under the MFMA phase; compiler waits vmcnt only at the ds_write below)
        const uint4* s = (const uint4*)(Bp + (size_t)(j + 1) * 4096);
        uint4 p0 = s[tid];
        uint4 p1 = s[256 + tid];

        __half2 xsj2[2];
        #pragma unroll
        for (int mt = 0; mt < 2; mt++) {
            __half v = xs[w][mt * 16 + m][j];
            xsj2[mt] = __halves2half2(v, v);
        }
        #pragma unroll
        for (int half = 0; half < 2; half++) {
            f16x8 bf[4];
            #pragma unroll
            for (int nt = 0; nt < 4; nt++)
                bf[nt] = *(const f16x8*)(&bbuf[cur][half * 2048 + nt * 512 + lane * 8]);
            #pragma unroll
            for (int mt = 0; mt < 2; mt++) {
                union { __half2 h[4]; f16x8 v; } u;
                #pragma unroll
                for (int q = 0; q < 4; q++)
                    u.h[q] = __hmul2(xsj2[mt], ehc2[mt][half][q]);
                #pragma unroll
                for (int nt = 0; nt < 4; nt++)
                    acc[mt][nt] = __builtin_amdgcn_mfma_f32_16x16x32_f16(
                        u.v, bf[nt], acc[mt][nt], 0, 0, 0);
            }
        }

        // write prefetched tile into the other buffer; barrier (its vmcnt/lgkm
        // drain is exactly the wait we need, and the previous-iteration barrier
        // guarantees no wave still reads bbuf[cur^1])
        uint4* d = (uint4*)bbuf[cur ^ 1];
        d[tid] = p0;
        d[256 + tid] = p1;
        __syncthreads();
        cur ^= 1;
    }

    // be2 K-extension (kt = 128,129 = tile 64, now in bbuf[cur]): A = xs row chunk
    #pragma unroll
    for (int half = 0; half < 2; half++) {
        f16x8 bf[4];
        #pragma unroll
        for (int nt = 0; nt < 4; nt++)
            bf[nt] = *(const f16x8*)(&bbuf[cur][half * 2048 + nt * 512 + lane * 8]);
        #pragma unroll
        for (int mt = 0; mt < 2; mt++) {
            f16x8 af = *(const f16x8*)(&xs[w][mt * 16 + m][half * 32 + quad * 8]);
            #pragma unroll
            for (int nt = 0; nt < 4; nt++)
                acc[mt][nt] = __builtin_amdgcn_mfma_f32_16x16x32_f16(
                    af, bf[nt], acc[mt][nt], 0, 0, 0);
        }
    }

    // C layout: col = lane&15 (i), row = quad*4 + reg (edge in tile)
    #pragma unroll
    for (int mt = 0; mt < 2; mt++) {
        #pragma unroll
        for (int r = 0; r < 4; r++) {
            const int row = w * 32 + mt * 16 + quad * 4 + r;
            const int t = tgt_s[row];
            if (t >= 0) {
                #pragma unroll
                for (int nt = 0; nt < 4; nt++)
                    atomicAdd(agg + (size_t)t * 64 + nt * 16 + m, acc[mt][nt][r]);
            }
        }
    }
}

// GRU via MFMA: wave = 16 nodes x 384 gate-cols (K=64). Weights LDS-staged once/block.
__global__ __launch_bounds__(256, 3) void gru_kernel(
    const float* __restrict__ agg, float* __restrict__ x, __half* __restrict__ xh,
    const __half* __restrict__ WG,
    const float* __restrict__ bih, const float* __restrict__ bhh)
{
    __shared__ __half wlds[24576];   // 48 KB
    const int tid = threadIdx.x;
    {
        const uint4* src = (const uint4*)WG;
        uint4* dst = (uint4*)wlds;
        #pragma unroll
        for (int i = 0; i < 12; i++) dst[i * 256 + tid] = src[i * 256 + tid];
    }
    __syncthreads();

    const int w = tid >> 6, lane = tid & 63, m = lane & 15, quad = lane >> 4;
    const int nbase = blockIdx.x * 64 + w * 16;
    const int anode = nbase + m;           // A-operand row
    const bool aok = (anode < NN);

    f16x8 a_agg[2], a_x[2];
    #pragma unroll
    for (int kt = 0; kt < 2; kt++) {
        const int koff = kt * 32 + quad * 8;
        if (aok) {
            const float* ap = agg + (size_t)anode * 64 + koff;
            float4 f0 = *(const float4*)ap;
            float4 f1 = *(const float4*)(ap + 4);
            union { __half2 h[4]; f16x8 v; } u;
            u.h[0] = __floats2half2_rn(f0.x, f0.y);
            u.h[1] = __floats2half2_rn(f0.z, f0.w);
            u.h[2] = __floats2half2_rn(f1.x, f1.y);
            u.h[3] = __floats2half2_rn(f1.z, f1.w);
            a_agg[kt] = u.v;
            a_x[kt] = *(const f16x8*)(xh + (size_t)anode * 64 + koff);
        } else {
            f16x8 z;
            #pragma unroll
            for (int i = 0; i < 8; i++) z[i] = (_Float16)0;
            a_agg[kt] = z; a_x[kt] = z;
        }
    }

    f32x4 acc[24];
    #pragma unroll
    for (int nt = 0; nt < 24; nt++)
        #pragma unroll
        for (int q = 0; q < 4; q++) acc[nt][q] = 0.f;

    #pragma unroll
    for (int kt = 0; kt < 2; kt++) {
        #pragma unroll
        for (int nt = 0; nt < 24; nt++) {
            f16x8 b = *(const f16x8*)(wlds + (kt * 24 + nt) * 512 + m * 32 + quad * 8);
            acc[nt] = __builtin_amdgcn_mfma_f32_16x16x32_f16(
                (nt < 12) ? a_agg[kt] : a_x[kt], b, acc[nt], 0, 0, 0);
        }
    }

    // epilogue: node = quad*4 + r (C row), h = t*16 + m (C col)
    #pragma unroll
    for (int t = 0; t < 4; t++) {
        const int h = t * 16 + m;
        const float bir = bih[h], biz = bih[64 + h], bin = bih[128 + h];
        const float bhr = bhh[h], bhz = bhh[64 + h], bhn = bhh[128 + h];
        #pragma unroll
        for (int r = 0; r < 4; r++) {
            const int nd = nbase + quad * 4 + r;
            if (nd >= NN) continue;
            float ir  = acc[t][r]      + bir;
            float iz  = acc[4 + t][r]  + biz;
            float in_ = acc[8 + t][r]  + bin;
            float hr  = acc[12 + t][r] + bhr;
            float hz  = acc[16 + t][r] + bhz;
            float hn  = acc[20 + t][r] + bhn;
            float rg = sigm(ir + hr);
            float z  = sigm(iz + hz);
            float n  = tanh_fast(in_ + rg * hn);
            float xold = x[(size_t)nd * 64 + h];
            float xn = (1.0f - z) * n + z * xold;
            x[(size_t)nd * 64 + h] = xn;
            xh[(size_t)nd * 64 + h] = __float2half(xn);
        }
    }
}

// out[n] = x[n].Wout + bout; pooled[batch[n]] += out[n]
__global__ __launch_bounds__(256) void pool_kernel(
    const float* __restrict__ x, const float* __restrict__ Wout,
    const float* __restrict__ bout, const int* __restrict__ batch,
    float* __restrict__ out)
{
    const int node = blockIdx.x * 256 + threadIdx.x;
    if (node >= NN) return;
    float acc = bout[0];
    const float4* xp = (const float4*)(x + (size_t)node * 64);
    #pragma unroll
    for (int i = 0; i < 16; i++) {
        float4 v = xp[i];
        acc += v.x * Wout[4*i] + v.y * Wout[4*i+1] + v.z * Wout[4*i+2] + v.w * Wout[4*i+3];
    }
    atomicAdd(out + batch[node], acc);
}

extern "C" void kernel_launch(void* const* d_in, const int* in_sizes, int n_in,
                              void* d_out, int out_size, void* d_ws, size_t ws_size,
                              hipStream_t stream)
{
    const float* nf   = (const float*)d_in[0];
    const float* ef   = (const float*)d_in[1];
    const int*   Esrc = (const int*)  d_in[2];
    const int*   Etgt = (const int*)  d_in[3];
    const int*   bat  = (const int*)  d_in[4];
    const float* Win  = (const float*)d_in[5];
    const float* bin_ = (const float*)d_in[6];
    const float* We1  = (const float*)d_in[7];
    const float* be1  = (const float*)d_in[8];
    const float* We2  = (const float*)d_in[9];
    const float* be2  = (const float*)d_in[10];
    const float* Wih  = (const float*)d_in[11];
    const float* bih  = (const float*)d_in[12];
    const float* Whh  = (const float*)d_in[13];
    const float* bhh  = (const float*)d_in[14];
    const float* Wout = (const float*)d_in[15];
    const float* bout = (const float*)d_in[16];

    char* ws = (char*)d_ws;
    float*  x   = (float*)(ws);                       // 12.8 MB
    float*  agg = (float*)(ws + 12800000);            // 12.8 MB
    __half* xh  = (__half*)(ws + 25600000);           // 6.4 MB
    __half* ehh = (__half*)(ws + 32000000);           // 12.8 MB
    __half* Bp  = (__half*)(ws + 44800000);           // 532,480 B
    __half* WG  = (__half*)(ws + 45400064);           // 49,152 B

    hipMemsetAsync(d_out, 0, NB * sizeof(float), stream);

    node_in_kernel<<<(NN * 64 + 255) / 256, 256, 0, stream>>>(nf, Win, bin_, x, xh);
    edge_l1_kernel<<<(NE * 64 + 255) / 256, 256, 0, stream>>>(ef, We1, be1, ehh);
    pack_b_kernel<<<(130 * 2048 + 255) / 256, 256, 0, stream>>>(We2, be2, Bp);
    pack_gru_kernel<<<(24576 + 255) / 256, 256, 0, stream>>>(Wih, Whh, WG);

    for (int t = 0; t < 3; t++) {
        hipMemsetAsync(agg, 0, (size_t)NN * 64 * sizeof(float), stream);
        msg_kernel<<<(NE + 127) / 128, 256, 0, stream>>>(xh, ehh, Bp, Esrc, Etgt, agg);
        gru_kernel<<<(NN + 63) / 64, 256, 0, stream>>>(agg, x, xh, WG, bih, bhh);
    }

    pool_kernel<<<(NN + 255) / 256, 256, 0, stream>>>(x, Wout, bout, bat, (float*)d_out);
}